// Round 4
// baseline (366.588 us; speedup 1.0000x reference)
//
#include <hip/hip_runtime.h>
#include <hip/hip_bf16.h>

typedef __attribute__((ext_vector_type(8))) short bf16x8;
typedef __attribute__((ext_vector_type(4))) short bf16x4;
typedef __attribute__((ext_vector_type(4))) float f32x4;
typedef __attribute__((address_space(3))) ushort lds_ushort;

#define MFMA32(a, b, c) __builtin_amdgcn_mfma_f32_16x16x32_bf16(a, b, c, 0, 0, 0)
#if __has_builtin(__builtin_amdgcn_mfma_f32_16x16x16bf16_1k)
#define HAVE_MFMA16K 1
#define MFMA16K(a, b, c) __builtin_amdgcn_mfma_f32_16x16x16bf16_1k(a, b, c, 0, 0, 0)
#else
#define HAVE_MFMA16K 0
#endif

// async global->LDS, 16B/lane; LDS dest = wave-uniform base + lane*16.
#define ASYNC16(g, l)                                                          \
    __builtin_amdgcn_global_load_lds(                                          \
        (const __attribute__((address_space(1))) unsigned int*)(g),            \
        (__attribute__((address_space(3))) unsigned int*)(l), 16, 0, 0)

// hw transpose read: per 16-lane group reads 128B window as 4x16 bf16
// row-major, lane l gets column (l&15). addr = window_base + (l&15)*8 bytes.
#define TR16(dst, addr, OFF)                                                   \
    asm volatile("ds_read_b64_tr_b16 %0, %1 offset:%2"                         \
                 : "=v"(dst) : "v"(addr), "i"(OFF))

__device__ __forceinline__ ushort f2bf(float f) {
    __hip_bfloat16 h = __float2bfloat16(f);  // RNE
    return *reinterpret_cast<ushort*>(&h);
}
// pack two f32 to bf16 pair in one instruction (T12; no builtin on gfx950).
__device__ __forceinline__ uint cvtpk(float a, float b) {
    uint r;
    asm("v_cvt_pk_bf16_f32 %0, %1, %2" : "=v"(r) : "v"(a), "v"(b));
    return r;
}

// log2(e)/sqrt(64), folded into Q projection -> attn does exp2(score) raw.
#define QSCALE 0.18033688011112042f

// ---------------------------------------------------------------------------
// fp32 -> bf16 convert (weights only now; X converts inside gemm3).
// ---------------------------------------------------------------------------
struct CvtArgs { const float* s[4]; ushort* d[4]; int nb[4]; };

__global__ __launch_bounds__(256) void cvtk(CvtArgs a) {
    const int z = blockIdx.y;
    if ((int)blockIdx.x >= a.nb[z]) return;
    const float* s = a.s[z];
    ushort* d = a.d[z];
    const size_t i = (size_t)blockIdx.x * 2048 + threadIdx.x * 8;
    float4 f0 = *(const float4*)&s[i];
    float4 f1 = *(const float4*)&s[i + 4];
    *(ushort4*)&d[i]     = make_ushort4(f2bf(f0.x), f2bf(f0.y), f2bf(f0.z), f2bf(f0.w));
    *(ushort4*)&d[i + 4] = make_ushort4(f2bf(f1.x), f2bf(f1.y), f2bf(f1.z), f2bf(f1.w));
}

// ---------------------------------------------------------------------------
// bf16 NT GEMM: out = (X@W^T + bias) * scale
//   xf32=1: X is fp32, converted in-register during A-staging (fuses cvt).
//   mode 0: bf16 out [B=4,H=16,S=2048,64]  (Q scaled, K, V)
//   mode 2: fp32 out [8192,1024]           (final projection)
// R3: simple 1-barrier double-buffer (R1/R2 proved the gemm is not
// latency-bound; syncthreads' full drain is the pipeline wait). At step k:
// write tile k+1's A from regs (loaded at k-1), DMA tile k+1's B, load tile
// k+2's A to regs, MFMA tile k. Cross-wave write/read hazards on As/Bs are
// separated by the barrier drain (ds_writes lgkm-drained + DMA vm-drained).
// XCD swizzle kept (per-XCD 4MB working set).
// ---------------------------------------------------------------------------
struct GemmArgs {
    const ushort* X[3]; const float* Xf[3]; const ushort* W[3];
    const float* B[3]; void* O[3]; int mode[3]; int xf32[3]; float scale[3];
};

__global__ __launch_bounds__(256) void gemm3(GemmArgs g) {
    __shared__ __attribute__((aligned(16))) ushort As[2][128][32];
    __shared__ __attribute__((aligned(16))) ushort Bs[2][128][32];

    const int z = blockIdx.z;
    const ushort* __restrict__ W = g.W[z];
    const float*  __restrict__ bias = g.B[z];
    const int mode = g.mode[z];
    const float scale = g.scale[z];

    const int tid  = threadIdx.x;
    const int lane = tid & 63;
    const int wave = tid >> 6;
    const int quad = lane >> 4;
    const int l16  = lane & 15;
    const int wm   = (wave >> 1) * 64;
    const int wn   = (wave & 1) * 64;

    const int flat = blockIdx.x + 8 * blockIdx.y;
    const int t    = (flat & 7) * 64 + (flat >> 3);
    const int m0   = (t >> 3) * 128;
    const int n0   = (t & 7) * 128;

    f32x4 acc[4][4];
#pragma unroll
    for (int i = 0; i < 4; i++)
#pragma unroll
        for (int j = 0; j < 4; j++) acc[i][j] = (f32x4)0.0f;

    // B staging: 2 ASYNC16 chunks/thread; chunk c: row c>>2, 16B col (c&3).
    auto stageB = [&](int buf, int k0) {
#pragma unroll
        for (int j = 0; j < 2; j++) {
            const int c   = j * 256 + tid;
            const int r   = c >> 2;
            const int col = (c & 3) * 8;
            ASYNC16(&W[(size_t)(n0 + r) * 1024 + k0 + col],
                    &Bs[buf][0][0] + (size_t)(j * 256 + wave * 64) * 8);
        }
    };

    if (g.xf32[z]) {
        // ---- fused-cvt A path: fp32 X -> regs -> bf16 ds_write ----
        const float* __restrict__ Xf = g.Xf[z];
        const int r0 = tid >> 2, cq = (tid & 3) * 8;
        float4 a0, a1, b0, b1;  // chunk0 (row r0), chunk1 (row 64+r0)
        auto loadA = [&](int k0) {
            a0 = *(const float4*)&Xf[(size_t)(m0 + r0) * 1024 + k0 + cq];
            a1 = *(const float4*)&Xf[(size_t)(m0 + r0) * 1024 + k0 + cq + 4];
            b0 = *(const float4*)&Xf[(size_t)(m0 + 64 + r0) * 1024 + k0 + cq];
            b1 = *(const float4*)&Xf[(size_t)(m0 + 64 + r0) * 1024 + k0 + cq + 4];
        };
        auto writeA = [&](int buf) {
            uint4 w;
            w.x = cvtpk(a0.x, a0.y); w.y = cvtpk(a0.z, a0.w);
            w.z = cvtpk(a1.x, a1.y); w.w = cvtpk(a1.z, a1.w);
            *(uint4*)&As[buf][r0][cq] = w;
            w.x = cvtpk(b0.x, b0.y); w.y = cvtpk(b0.z, b0.w);
            w.z = cvtpk(b1.x, b1.y); w.w = cvtpk(b1.z, b1.w);
            *(uint4*)&As[buf][64 + r0][cq] = w;
        };

        loadA(0);
        writeA(0);
        stageB(0, 0);
        loadA(32);  // tile 1 -> regs

        int cur = 0;
        for (int k0 = 0; k0 < 1024; k0 += 32) {
            __syncthreads();  // As/Bs[cur] ready (lgkm+vm drained at barrier)
            if (k0 + 32 < 1024) {
                writeA(cur ^ 1);          // tile k+1 from regs
                stageB(cur ^ 1, k0 + 32); // tile k+1 DMA
            }
            if (k0 + 64 < 1024) loadA(k0 + 64);  // tile k+2 -> regs

            bf16x8 af[4], bfr[4];
#pragma unroll
            for (int i = 0; i < 4; i++)
                af[i] = *(const bf16x8*)&As[cur][wm + i * 16 + l16][quad * 8];
#pragma unroll
            for (int j = 0; j < 4; j++)
                bfr[j] = *(const bf16x8*)&Bs[cur][wn + j * 16 + l16][quad * 8];
#pragma unroll
            for (int i = 0; i < 4; i++)
#pragma unroll
                for (int j = 0; j < 4; j++)
                    acc[i][j] = MFMA32(af[i], bfr[j], acc[i][j]);
            cur ^= 1;
        }
    } else {
        // ---- bf16 A path: both sides DMA ----
        const ushort* __restrict__ X = g.X[z];
        auto stageA = [&](int buf, int k0) {
#pragma unroll
            for (int j = 0; j < 2; j++) {
                const int c   = j * 256 + tid;
                const int r   = c >> 2;
                const int col = (c & 3) * 8;
                ASYNC16(&X[(size_t)(m0 + r) * 1024 + k0 + col],
                        &As[buf][0][0] + (size_t)(j * 256 + wave * 64) * 8);
            }
        };
        stageA(0, 0);
        stageB(0, 0);
        int cur = 0;
        for (int k0 = 0; k0 < 1024; k0 += 32) {
            __syncthreads();
            if (k0 + 32 < 1024) {
                stageA(cur ^ 1, k0 + 32);
                stageB(cur ^ 1, k0 + 32);
            }
            bf16x8 af[4], bfr[4];
#pragma unroll
            for (int i = 0; i < 4; i++)
                af[i] = *(const bf16x8*)&As[cur][wm + i * 16 + l16][quad * 8];
#pragma unroll
            for (int j = 0; j < 4; j++)
                bfr[j] = *(const bf16x8*)&Bs[cur][wn + j * 16 + l16][quad * 8];
#pragma unroll
            for (int i = 0; i < 4; i++)
#pragma unroll
                for (int j = 0; j < 4; j++)
                    acc[i][j] = MFMA32(af[i], bfr[j], acc[i][j]);
            cur ^= 1;
        }
    }

    // C/D: col = lane&15 (n), row = quad*4 + reg (m).
#pragma unroll
    for (int i = 0; i < 4; i++) {
#pragma unroll
        for (int j = 0; j < 4; j++) {
            const int n  = n0 + wn + j * 16 + l16;
            const float bb = bias[n];
#pragma unroll
            for (int r = 0; r < 4; r++) {
                const int m = m0 + wm + i * 16 + quad * 4 + r;
                const float val = (acc[i][j][r] + bb) * scale;
                if (mode == 2) {
                    ((float*)g.O[z])[(size_t)m * 1024 + n] = val;
                } else {
                    const int bat = m >> 11, s = m & 2047, h = n >> 6, d = n & 63;
                    ((ushort*)g.O[z])[((size_t)((bat * 16 + h) * 2048 + s)) * 64 + d]
                        = f2bf(val);
                }
            }
        }
    }
}

// ---------------------------------------------------------------------------
// Attention, P-in-registers (unchanged from R2; 97% combined pipe util).
// ---------------------------------------------------------------------------
__global__ __launch_bounds__(256, 4) void attn(
    const ushort* __restrict__ Qp, const ushort* __restrict__ Kp,
    const ushort* __restrict__ Vp, ushort* __restrict__ ctx)
{
    __shared__ __attribute__((aligned(16))) ushort Ks[2][2 * 64 * 32];  // 2x8KB
    __shared__ __attribute__((aligned(16))) ushort Vs[2][64 * 64];      // 2x8KB

    const int tid  = threadIdx.x;
    const int lane = tid & 63;
    const int wave = tid >> 6;
    const int quad = lane >> 4;
    const int l16  = lane & 15;

    const int id = blockIdx.x;
    const int bh = (id & 7) * 8 + ((id >> 3) & 7);  // XCD-contiguous bh
    const int q0 = (id >> 6) * 128;
    const int b  = bh >> 4, h = bh & 15;

    const ushort* Qg = Qp + ((size_t)bh * 2048 + q0) * 64;
    const ushort* Kg = Kp + (size_t)bh * 2048 * 64;
    const ushort* Vg = Vp + (size_t)bh * 2048 * 64;

    // Loop-invariant Q fragments (B-operand: n=l16=query, k=quad*8+e).
    bf16x8 aq[2][2];
#pragma unroll
    for (int st = 0; st < 2; st++)
#pragma unroll
        for (int kk = 0; kk < 2; kk++)
            aq[st][kk] = *(const bf16x8*)&Qg[(size_t)(wave * 32 + st * 16 + l16) * 64
                                            + kk * 32 + quad * 8];

    f32x4 o[2][4];
#pragma unroll
    for (int st = 0; st < 2; st++)
#pragma unroll
        for (int jd = 0; jd < 4; jd++) o[st][jd] = (f32x4)0.0f;
#if HAVE_MFMA16K
    f32x4 ls[2] = {(f32x4)0.0f, (f32x4)0.0f};  // row sums, o-compatible layout
    union { uint u[2]; bf16x4 v; } ones;
    ones.u[0] = 0x3F803F80u; ones.u[1] = 0x3F803F80u;  // bf16 1.0 x4
#else
    float lsum[2] = {0.f, 0.f};
#endif

    // K tile: natural [half][row][32] layout. V tile: 4x16-subtiled V' via
    // source-swizzled async chunks; global src stays 128B-coalesced per 8 lanes.
    auto stage = [&](int buf, int n0) {
#pragma unroll
        for (int j = 0; j < 2; j++) {
            const int c    = j * 256 + tid;
            const int colq = c & 3;
            const int row  = (c >> 2) & 63;
            const int half = c >> 8;
            ASYNC16(&Kg[(size_t)(n0 + row) * 64 + half * 32 + colq * 8],
                    &Ks[buf][0] + (size_t)(j * 256 + wave * 64) * 8);
        }
#pragma unroll
        for (int j = 0; j < 2; j++) {
            const int c   = j * 256 + tid;
            const int key = ((c >> 5) << 2) | ((c >> 1) & 3);
            const int d   = (((c >> 3) & 3) << 4) | ((c & 1) << 3);
            ASYNC16(&Vg[(size_t)(n0 + key) * 64 + d],
                    &Vs[buf][0] + (size_t)(j * 256 + wave * 64) * 8);
        }
    };

    stage(0, 0);
    int cur = 0;

    for (int n0 = 0; n0 < 2048; n0 += 64) {
        __syncthreads();  // drains vmcnt: buf 'cur' is ready; prev reads done
        if (n0 + 64 < 2048) stage(cur ^ 1, n0 + 64);  // flies under compute

        // ---- S^T: 8 tiles (kb keys x st strips), exp2 + pack in-register ----
        uint pk[4][2][2];
#pragma unroll
        for (int kb = 0; kb < 4; kb++) {
            bf16x8 kf0 = *(const bf16x8*)&Ks[cur][(size_t)(kb * 16 + l16) * 32 + quad * 8];
            bf16x8 kf1 = *(const bf16x8*)&Ks[cur][(size_t)(64 + kb * 16 + l16) * 32 + quad * 8];
#pragma unroll
            for (int st = 0; st < 2; st++) {
                f32x4 s = (f32x4)0.0f;
                s = MFMA32(kf0, aq[st][0], s);
                s = MFMA32(kf1, aq[st][1], s);
                float e0 = __builtin_amdgcn_exp2f(s[0]);
                float e1 = __builtin_amdgcn_exp2f(s[1]);
                float e2 = __builtin_amdgcn_exp2f(s[2]);
                float e3 = __builtin_amdgcn_exp2f(s[3]);
                pk[kb][st][0] = cvtpk(e0, e1);
                pk[kb][st][1] = cvtpk(e2, e3);
#if !HAVE_MFMA16K
                lsum[st] += (e0 + e1) + (e2 + e3);
#endif
            }
        }

#if HAVE_MFMA16K
        // ---- PV: B-frags via hw transpose reads from subtiled V' ----
        const lds_ushort* vp = (const lds_ushort*)&Vs[cur][0] + quad * 256 + l16 * 4;
        bf16x4 vf[4][4];  // [jd][kb]
#define TRISSUE(JD)                                                            \
        TR16(vf[JD][0], vp, (JD) * 128 + 0);                                   \
        TR16(vf[JD][1], vp, (JD) * 128 + 2048);                                \
        TR16(vf[JD][2], vp, (JD) * 128 + 4096);                                \
        TR16(vf[JD][3], vp, (JD) * 128 + 6144);
        TRISSUE(0) TRISSUE(1) TRISSUE(2) TRISSUE(3)

        // Row-sum MFMAs (register-only) fill the tr-read latency window:
        // C[q][*] += sum_k P[q][k]; reg r holds query quad*4+r = o's layout.
#pragma unroll
        for (int kb = 0; kb < 4; kb++) {
#pragma unroll
            for (int st = 0; st < 2; st++) {
                union { uint u[2]; bf16x4 v; } pf;
                pf.u[0] = pk[kb][st][0];
                pf.u[1] = pk[kb][st][1];
                ls[st] = MFMA16K(pf.v, ones.v, ls[st]);
            }
        }

        // counted lgkmcnt: jd group ready when <=12-4*jd outstanding (FIFO,
        // trs are oldest). sched_barrier(0) after each wait (rule #18).
#define PVWAIT(N)                                                              \
        asm volatile("s_waitcnt lgkmcnt(" #N ")" ::: "memory");                \
        __builtin_amdgcn_sched_barrier(0);
#define PVJD(JD)                                                               \
        _Pragma("unroll")                                                      \
        for (int kb = 0; kb < 4; kb++) {                                       \
            _Pragma("unroll")                                                  \
            for (int st = 0; st < 2; st++) {                                   \
                union { uint u[2]; bf16x4 v; } pf;                             \
                pf.u[0] = pk[kb][st][0];                                       \
                pf.u[1] = pk[kb][st][1];                                       \
                o[st][JD] = MFMA16K(pf.v, vf[JD][kb], o[st][JD]);              \
            }                                                                  \
        }
        __builtin_amdgcn_s_setprio(1);
        PVWAIT(12) PVJD(0)
        PVWAIT(8)  PVJD(1)
        PVWAIT(4)  PVJD(2)
        PVWAIT(0)  PVJD(3)
        __builtin_amdgcn_s_setprio(0);
#else
        // Fallback: assemble K=32 A-frags via ds_bpermute, gather V from the
        // subtiled V' with scalar reads, PV with MFMA32. (Correctness path.)
        const int addr0 = 4 * ((2 * (quad & 1)) * 16 + l16);
        const int addr1 = addr0 + 64;
#pragma unroll
        for (int kt = 0; kt < 2; kt++) {
            bf16x8 apf[2];
#pragma unroll
            for (int st = 0; st < 2; st++) {
                union { uint u[4]; bf16x8 v; } t;
#pragma unroll
                for (int j = 0; j < 4; j++) {
                    uint src = (quad & 2) ? pk[kt * 2 + 1][st][j & 1]
                                          : pk[kt * 2][st][j & 1];
                    t.u[j] = (uint)__builtin_amdgcn_ds_bpermute(
                        (j >> 1) ? addr1 : addr0, (int)src);
                }
                apf[st] = t.v;
            }
#pragma unroll
            for (int jd = 0; jd < 4; jd++) {
                union { ushort s[8]; bf16x8 v; } vv;
#pragma unroll
                for (int e = 0; e < 8; e++) {
                    const int key = kt * 32 + quad * 8 + e;
                    const int d   = jd * 16 + l16;
                    vv.s[e] = Vs[cur][(key >> 2) * 256 + (d >> 4) * 64
                                      + (key & 3) * 16 + (d & 15)];
                }
#pragma unroll
                for (int st = 0; st < 2; st++)
                    o[st][jd] = MFMA32(apf[st], vv.v, o[st][jd]);
            }
        }
#endif
        cur ^= 1;
    }

#if HAVE_MFMA16K
    // ls[st][r] is already the row sum for query quad*4+r — no shuffles.
#pragma unroll
    for (int st = 0; st < 2; st++) {
        float inv[4];
#pragma unroll
        for (int r = 0; r < 4; r++) inv[r] = 1.0f / ls[st][r];
#pragma unroll
        for (int jd = 0; jd < 4; jd++) {
#pragma unroll
            for (int r = 0; r < 4; r++) {
                const int s = q0 + wave * 32 + st * 16 + quad * 4 + r;
                ctx[((size_t)(b * 2048 + s)) * 1024 + h * 64 + jd * 16 + l16] =
                    f2bf(o[st][jd][r] * inv[r]);
            }
        }
    }
#else
    // lsum holds per-(l16,quad) partials for query=l16: reduce over quads.
#pragma unroll
    for (int st = 0; st < 2; st++) {
        float lsv = lsum[st];
        lsv += __shfl_xor(lsv, 16, 64);
        lsv += __shfl_xor(lsv, 32, 64);
        float inv[4];
#pragma unroll
        for (int r = 0; r < 4; r++)
            inv[r] = 1.0f / __shfl(lsv, quad * 4 + r, 64);
#pragma unroll
        for (int jd = 0; jd < 4; jd++) {
#pragma unroll
            for (int r = 0; r < 4; r++) {
                const int s = q0 + wave * 32 + st * 16 + quad * 4 + r;
                ctx[((size_t)(b * 2048 + s)) * 1024 + h * 64 + jd * 16 + l16] =
                    f2bf(o[st][jd][r] * inv[r]);
            }
        }
    }
#endif
}

extern "C" void kernel_launch(void* const* d_in, const int* in_sizes, int n_in,
                              void* d_out, int out_size, void* d_ws, size_t ws_size,
                              hipStream_t stream) {
    const float* q    = (const float*)d_in[0];
    const float* k    = (const float*)d_in[1];
    const float* v    = (const float*)d_in[2];
    const float* wq_w = (const float*)d_in[3];
    const float* wq_b = (const float*)d_in[4];
    const float* wk_w = (const float*)d_in[5];
    const float* wk_b = (const float*)d_in[6];
    const float* wv_w = (const float*)d_in[7];
    const float* wv_b = (const float*)d_in[8];
    const float* wo_w = (const float*)d_in[9];
    const float* wo_b = (const float*)d_in[10];
    float* out = (float*)d_out;

    const size_t NE = (size_t)4 * 2048 * 1024;
    const size_t NW = (size_t)1024 * 1024;
    const size_t need_fused = (4 * NE + 4 * NW) * 2;

    dim3 blk(256);

    if (ws_size >= need_fused) {
        ushort* Wq = (ushort*)d_ws;
        ushort* Wk = Wq + NW;
        ushort* Wv = Wk + NW;
        ushort* Wo = Wv + NW;
        ushort* Qp = Wo + NW;
        ushort* Kp = Qp + NE;
        ushort* Vp = Kp + NE;
        ushort* ctx = Vp + NE;

        CvtArgs ca;
        ca.s[0]=wq_w; ca.d[0]=Wq; ca.nb[0]=512;
        ca.s[1]=wk_w; ca.d[1]=Wk; ca.nb[1]=512;
        ca.s[2]=wv_w; ca.d[2]=Wv; ca.nb[2]=512;
        ca.s[3]=wo_w; ca.d[3]=Wo; ca.nb[3]=512;
        cvtk<<<dim3(512, 4), blk, 0, stream>>>(ca);

        GemmArgs ga;
        ga.Xf[0]=q; ga.Xf[1]=k; ga.Xf[2]=v;
        ga.X[0]=ga.X[1]=ga.X[2]=nullptr;
        ga.W[0]=Wq; ga.W[1]=Wk; ga.W[2]=Wv;
        ga.B[0]=wq_b; ga.B[1]=wk_b; ga.B[2]=wv_b;
        ga.O[0]=Qp; ga.O[1]=Kp; ga.O[2]=Vp;
        ga.mode[0]=ga.mode[1]=ga.mode[2]=0;
        ga.xf32[0]=ga.xf32[1]=ga.xf32[2]=1;
        ga.scale[0]=QSCALE; ga.scale[1]=1.0f; ga.scale[2]=1.0f;
        gemm3<<<dim3(8, 64, 3), blk, 0, stream>>>(ga);

        attn<<<dim3(1024), blk, 0, stream>>>(Qp, Kp, Vp, ctx);

        GemmArgs go;
        for (int i = 0; i < 3; i++) {
            go.X[i]=ctx; go.Xf[i]=nullptr; go.W[i]=Wo; go.B[i]=wo_b;
            go.O[i]=out; go.mode[i]=2; go.xf32[i]=0; go.scale[i]=1.0f;
        }
        gemm3<<<dim3(8, 64, 1), blk, 0, stream>>>(go);
    } else {
        // Serial fallback: one W buffer reused (needs (4NE+NW)*2 = 66 MB).
        ushort* Qp  = (ushort*)d_ws;
        ushort* Kp  = Qp + NE;
        ushort* Vp  = Kp + NE;
        ushort* ctx = Vp + NE;
        ushort* Wb  = ctx + NE;

        const float* xs[3] = {q, k, v};
        const float* ws[3] = {wq_w, wk_w, wv_w};
        const float* bs[3] = {wq_b, wk_b, wv_b};
        ushort* os[3] = {Qp, Kp, Vp};
        for (int p = 0; p < 3; p++) {
            CvtArgs c;
            c.s[0]=ws[p]; c.d[0]=Wb; c.nb[0]=512;
            for (int i = 1; i < 4; i++) { c.s[i]=ws[p]; c.d[i]=Wb; c.nb[i]=0; }
            cvtk<<<dim3(512, 1), blk, 0, stream>>>(c);
            GemmArgs gg;
            for (int i = 0; i < 3; i++) {
                gg.Xf[i]=xs[p]; gg.X[i]=nullptr; gg.W[i]=Wb; gg.B[i]=bs[p];
                gg.O[i]=os[p]; gg.mode[i]=0; gg.xf32[i]=1;
                gg.scale[i]=(p == 0) ? QSCALE : 1.0f;
            }
            gemm3<<<dim3(8, 64, 1), blk, 0, stream>>>(gg);
        }

        attn<<<dim3(1024), blk, 0, stream>>>(Qp, Kp, Vp, ctx);

        CvtArgs c;
        c.s[0]=wo_w; c.d[0]=Wb; c.nb[0]=512;
        for (int i = 1; i < 4; i++) { c.s[i]=wo_w; c.d[i]=Wb; c.nb[i]=0; }
        cvtk<<<dim3(512, 1), blk, 0, stream>>>(c);
        GemmArgs go;
        for (int i = 0; i < 3; i++) {
            go.X[i]=ctx; go.Xf[i]=nullptr; go.W[i]=Wb; go.B[i]=wo_b;
            go.O[i]=out; go.mode[i]=2; go.xf32[i]=0; go.scale[i]=1.0f;
        }
        gemm3<<<dim3(8, 64, 1), blk, 0, stream>>>(go);
    }
}